// Round 1
// baseline (227.525 us; speedup 1.0000x reference)
//
#include <hip/hip_runtime.h>

// ProgressiveDropout: out[i,j] = x[i,j] if j < samples[i] else 0
// B = 8192 rows, C = 4096 cols, float32.
// Memory-bound: 256 MiB total traffic -> roofline ~43 us at 6.3 TB/s.

#define B_ROWS 8192
#define C_COLS 4096
#define C_VEC  (C_COLS / 4)   // 1024 float4 per row (power of 2)

__global__ __launch_bounds__(256) void progressive_dropout_kernel(
    const float* __restrict__ x,
    const int*   __restrict__ samples,
    float*       __restrict__ out)
{
    const long long total = (long long)B_ROWS * C_VEC;  // 8.39M float4s
    const long long stride = (long long)gridDim.x * blockDim.x;

    for (long long idx = (long long)blockIdx.x * blockDim.x + threadIdx.x;
         idx < total; idx += stride)
    {
        const int row  = (int)(idx >> 10);        // idx / C_VEC
        const int col4 = (int)(idx & (C_VEC - 1)); // idx % C_VEC
        const int s    = samples[row];             // wave-broadcast via cache
        const int c0   = col4 << 2;                // base column of this float4

        float4 v = reinterpret_cast<const float4*>(x)[idx];
        v.x = (c0 + 0 < s) ? v.x : 0.0f;
        v.y = (c0 + 1 < s) ? v.y : 0.0f;
        v.z = (c0 + 2 < s) ? v.z : 0.0f;
        v.w = (c0 + 3 < s) ? v.w : 0.0f;
        reinterpret_cast<float4*>(out)[idx] = v;
    }
}

extern "C" void kernel_launch(void* const* d_in, const int* in_sizes, int n_in,
                              void* d_out, int out_size, void* d_ws, size_t ws_size,
                              hipStream_t stream)
{
    const float* x       = (const float*)d_in[0];
    const int*   samples = (const int*)d_in[1];
    float*       out     = (float*)d_out;

    const int block = 256;
    // Grid-stride: cap at 256 CU x 32 blocks; total work = 8.39M float4s.
    const long long total = (long long)B_ROWS * C_VEC;
    int grid = (int)((total + block - 1) / block);
    if (grid > 8192) grid = 8192;

    progressive_dropout_kernel<<<grid, block, 0, stream>>>(x, samples, out);
}

// Round 5
// 216.923 us; speedup vs baseline: 1.0489x; 1.0489x over previous
//
#include <hip/hip_runtime.h>

// ProgressiveDropout: out[i,j] = x[i,j] if j < samples[i] else 0
// B = 8192 rows, C = 4096 cols, float32.
// Must WRITE all 128 MiB, but only need to READ x where j < samples[i]
// (expected ~half). Skip loads for fully-masked float4s; nontemporal
// loads/stores since both streams are touch-once.

#define B_ROWS 8192
#define C_COLS 4096
#define C_VEC  (C_COLS / 4)   // 1024 float4 per row (power of 2)

typedef float f4 __attribute__((ext_vector_type(4)));

__global__ __launch_bounds__(256) void progressive_dropout_kernel(
    const f4*  __restrict__ x,
    const int* __restrict__ samples,
    f4*        __restrict__ out)
{
    const int total  = B_ROWS * C_VEC;             // 8,388,608 (fits int)
    const int stride = gridDim.x * blockDim.x;

    for (int idx = blockIdx.x * blockDim.x + threadIdx.x;
         idx < total; idx += stride)
    {
        const int row = idx >> 10;                 // idx / C_VEC
        const int c0  = (idx & (C_VEC - 1)) << 2;  // base column of this float4
        const int s   = samples[row];              // wave-uniform (64 lanes = 256 cols, 1 row)

        f4 v;
        if (c0 >= s) {
            // fully masked: no load needed
            v.x = 0.0f; v.y = 0.0f; v.z = 0.0f; v.w = 0.0f;
        } else {
            v = __builtin_nontemporal_load(&x[idx]);
            if (c0 + 4 > s) {                      // boundary float4 only
                v.x = (c0 + 0 < s) ? v.x : 0.0f;
                v.y = (c0 + 1 < s) ? v.y : 0.0f;
                v.z = (c0 + 2 < s) ? v.z : 0.0f;
                v.w = (c0 + 3 < s) ? v.w : 0.0f;
            }
        }
        __builtin_nontemporal_store(v, &out[idx]);
    }
}

extern "C" void kernel_launch(void* const* d_in, const int* in_sizes, int n_in,
                              void* d_out, int out_size, void* d_ws, size_t ws_size,
                              hipStream_t stream)
{
    const f4*  x       = (const f4*)d_in[0];
    const int* samples = (const int*)d_in[1];
    f4*        out     = (f4*)d_out;

    const int block = 256;
    const int total = B_ROWS * C_VEC;
    int grid = (total + block - 1) / block;
    if (grid > 8192) grid = 8192;   // grid-stride, 4 float4s/thread

    progressive_dropout_kernel<<<grid, block, 0, stream>>>(x, samples, out);
}